// Round 2
// baseline (193.487 us; speedup 1.0000x reference)
//
#include <hip/hip_runtime.h>

// Haar wavedec, 12 levels on last dim (4096) == row-sum * (1/sqrt(2))^12
// = row-sum / 64. Pure memory-bound row reduction: 65536 rows x 4096 fp32.
//
// One wave (64 lanes) per row; persistent grid (2048 blocks = 256 CU x 8)
// grid-strides over rows so each wave handles 8 rows back-to-back. All loads
// are lane-contiguous float4 (1 KiB per wave per instruction, fully
// coalesced). 6-step __shfl_xor wave reduce, single store per row.

__global__ __launch_bounds__(256) void haar_rowsum_kernel(
    const float* __restrict__ x, float* __restrict__ out, int nrows) {
    const int lane          = threadIdx.x & 63;
    const int wave_in_block = threadIdx.x >> 6;
    const int waves_total   = (gridDim.x * blockDim.x) >> 6;   // 8192
    int row = blockIdx.x * (blockDim.x >> 6) + wave_in_block;

    for (; row < nrows; row += waves_total) {
        const float4* rowp =
            reinterpret_cast<const float4*>(x + (size_t)row * 4096);

        float4 acc = make_float4(0.f, 0.f, 0.f, 0.f);
#pragma unroll
        for (int j = 0; j < 16; ++j) {
            float4 v = rowp[j * 64 + lane];
            acc.x += v.x;
            acc.y += v.y;
            acc.z += v.z;
            acc.w += v.w;
        }
        float s = (acc.x + acc.y) + (acc.z + acc.w);

        // wave-64 butterfly reduction
#pragma unroll
        for (int off = 32; off >= 1; off >>= 1)
            s += __shfl_xor(s, off, 64);

        if (lane == 0)
            out[row] = s * 0.015625f;  // (1/sqrt(2))^12 == 1/64 exactly
    }
}

extern "C" void kernel_launch(void* const* d_in, const int* in_sizes, int n_in,
                              void* d_out, int out_size, void* d_ws, size_t ws_size,
                              hipStream_t stream) {
    const float* x = (const float*)d_in[0];
    float* out = (float*)d_out;
    const int nrows = out_size;          // 128*512 = 65536 rows
    const int threads = 256;             // 4 waves -> 4 rows per iteration
    const int blocks = 2048;             // 256 CU x 8 blocks, grid-stride x8
    haar_rowsum_kernel<<<blocks, threads, 0, stream>>>(x, out, nrows);
}

// Round 4
// 164.902 us; speedup vs baseline: 1.1733x; 1.1733x over previous
//
#include <hip/hip_runtime.h>

// Haar wavedec, 12 levels on last dim (4096) == row-sum * (1/sqrt(2))^12
// = row-sum / 64. Pure memory-bound row reduction: 65536 rows x 4096 fp32.
//
// Round-1 structure (full 16384-block dispatch, one wave per row — measured
// faster than persistent-grid round 2), plus non-temporal loads: the 1.07 GB
// input is a single-use stream 4x the 256 MB L3, so skip cache retention.
// NT builtin needs a clang ext_vector type, not HIP's struct float4.

typedef float floatx4 __attribute__((ext_vector_type(4)));

__global__ __launch_bounds__(256) void haar_rowsum_kernel(
    const float* __restrict__ x, float* __restrict__ out, int nrows) {
    const int gtid = blockIdx.x * blockDim.x + threadIdx.x;
    const int row  = gtid >> 6;          // one wave64 per row
    const int lane = threadIdx.x & 63;
    if (row >= nrows) return;

    const floatx4* rowp =
        reinterpret_cast<const floatx4*>(x + (size_t)row * 4096);

    floatx4 acc = (floatx4)0.f;
#pragma unroll
    for (int j = 0; j < 16; ++j) {
        floatx4 v = __builtin_nontemporal_load(rowp + j * 64 + lane);
        acc += v;
    }
    float s = (acc.x + acc.y) + (acc.z + acc.w);

    // wave-64 butterfly reduction
#pragma unroll
    for (int off = 32; off >= 1; off >>= 1)
        s += __shfl_xor(s, off, 64);

    if (lane == 0)
        out[row] = s * 0.015625f;  // (1/sqrt(2))^12 == 1/64 exactly
}

extern "C" void kernel_launch(void* const* d_in, const int* in_sizes, int n_in,
                              void* d_out, int out_size, void* d_ws, size_t ws_size,
                              hipStream_t stream) {
    const float* x = (const float*)d_in[0];
    float* out = (float*)d_out;
    const int nrows = out_size;              // 128*512 = 65536 rows
    const int threads = 256;                 // 4 waves -> 4 rows per block
    const int rows_per_block = threads / 64;
    const int blocks = (nrows + rows_per_block - 1) / rows_per_block;
    haar_rowsum_kernel<<<blocks, threads, 0, stream>>>(x, out, nrows);
}